// Round 5
// baseline (2980.068 us; speedup 1.0000x reference)
//
#include <hip/hip_runtime.h>
#include <hip/hip_bf16.h>

// GroupedMLP: E=8, T=1024, H=2048, I=5632
// Round 5: same 256x256x64 8-wave structure as round 4 (mt-innermost L2
// ordering, T2 swizzle via ws layouts, counted vmcnt, setprio), but the
// register-fragment ds_reads are SOFTWARE-PIPELINED one MFMA-cluster ahead:
//   tail:   read F1(t+1) = a-lo + b-lo      (after vmcnt(8)+barrier)
//   top:    read F2(t)   = a-hi             (before q00's barrier)
//   q00 MFMA (F1)  | F3(t) = b-hi issued    (before q10's barrier)
//   q10 MFMA (F2)  | q11 MFMA (F3)
//   stage(t+2) issued, then q01 MFMA (a-lo x b-hi) overlaps the load issue.
// Compiler emits counted lgkmcnt per dataflow, so LDS-read + stage latency
// hides under MFMA instead of adding to it (round-4 loss: 2890 vs ~1000 cyc
// per K-tile).

#define EXPERTS 8
#define TOK     1024
#define HID     2048
#define INTER   5632
#define I2      (2 * INTER)

typedef __bf16 bf16x8 __attribute__((ext_vector_type(8)));
typedef float  f32x4  __attribute__((ext_vector_type(4)));

__device__ __forceinline__ unsigned short f2bf(float f) {
    union { float f; unsigned u; } v; v.f = f;
    unsigned r = v.u + 0x7FFFu + ((v.u >> 16) & 1u);   // RNE
    return (unsigned short)(r >> 16);
}

__device__ __forceinline__ void gload_lds16(const void* g, void* l) {
    __builtin_amdgcn_global_load_lds(
        (const __attribute__((address_space(1))) void*)g,
        (__attribute__((address_space(3))) void*)l, 16, 0, 0);
}

// swizzled fragment read: tile is [256][64] bf16, element k-slot XORed by row&7
__device__ __forceinline__ bf16x8 ldfrag(const unsigned short* S, int R, int kb) {
    int off = R * 64 + (kb ^ ((R & 7) << 3));
    return *reinterpret_cast<const bf16x8*>(S + off);
}

// ---------------- converts (write swizzled ws layouts) ----------------

__global__ __launch_bounds__(256) void k_cvt_x(const float* __restrict__ X,
                                               unsigned short* __restrict__ Xb) {
    size_t base = ((size_t)blockIdx.x * 256 + threadIdx.x) * 8;
    int row = (int)(base >> 11);
    int k   = (int)(base & (HID - 1));
    int kp  = k ^ ((row & 7) << 3);
    float4 v0 = *reinterpret_cast<const float4*>(X + base);
    float4 v1 = *reinterpret_cast<const float4*>(X + base + 4);
    uint4 o;
    o.x = (unsigned)f2bf(v0.x) | ((unsigned)f2bf(v0.y) << 16);
    o.y = (unsigned)f2bf(v0.z) | ((unsigned)f2bf(v0.w) << 16);
    o.z = (unsigned)f2bf(v1.x) | ((unsigned)f2bf(v1.y) << 16);
    o.w = (unsigned)f2bf(v1.z) | ((unsigned)f2bf(v1.w) << 16);
    *reinterpret_cast<uint4*>(Xb + (size_t)row * HID + kp) = o;
}

__global__ __launch_bounds__(256) void k_cvt_w1(const float* __restrict__ W1,
                                                unsigned short* __restrict__ W1T) {
    __shared__ unsigned short lds[64][72];
    const int bid = blockIdx.x;
    const int hb = bid % (HID / 64);
    const int pb = (bid / (HID / 64)) % (I2 / 64);
    const int e  = bid / ((HID / 64) * (I2 / 64));
    const int h0 = hb * 64, p0 = pb * 64, n0 = p0 >> 1;
    const float* w1e = W1 + (size_t)e * HID * I2;
    const int t = threadIdx.x;
#pragma unroll
    for (int it = 0; it < 16; ++it) {
        int lin   = it * 256 + t;
        int n_off = lin & 31;
        int c     = (lin >> 5) & 1;
        int h_off = lin >> 6;
        float v = w1e[(size_t)(h0 + h_off) * I2 + c * INTER + n0 + n_off];
        lds[2 * n_off + c][h_off] = f2bf(v);
    }
    __syncthreads();
    unsigned short* o = W1T + (size_t)e * I2 * HID;
#pragma unroll
    for (int it = 0; it < 4; ++it) {
        int lin = it * 256 + t;
        int r   = lin >> 4;
        int co  = (lin & 15) * 4;
        int cop = co ^ ((r & 7) << 3);
        ushort4 v = *reinterpret_cast<ushort4*>(&lds[r][co]);
        *reinterpret_cast<ushort4*>(o + (size_t)(p0 + r) * HID + h0 + cop) = v;
    }
}

__global__ __launch_bounds__(256) void k_cvt_w2(const float* __restrict__ W2,
                                                unsigned short* __restrict__ W2T) {
    __shared__ unsigned short lds[64][72];
    const int bid = blockIdx.x;
    const int ib = bid % (INTER / 64);
    const int hb = (bid / (INTER / 64)) % (HID / 64);
    const int e  = bid / ((INTER / 64) * (HID / 64));
    const int i0 = ib * 64, h0 = hb * 64;
    const float* w2e = W2 + (size_t)e * INTER * HID;
    const int t = threadIdx.x;
#pragma unroll
    for (int it = 0; it < 16; ++it) {
        int lin   = it * 256 + t;
        int h_off = lin & 63;
        int i_off = lin >> 6;
        float v = w2e[(size_t)(i0 + i_off) * HID + h0 + h_off];
        lds[h_off][i_off] = f2bf(v);
    }
    __syncthreads();
    unsigned short* o = W2T + (size_t)e * HID * INTER;
#pragma unroll
    for (int it = 0; it < 4; ++it) {
        int lin = it * 256 + t;
        int r   = lin >> 4;
        int co  = (lin & 15) * 4;
        int cop = co ^ ((r & 7) << 3);
        ushort4 v = *reinterpret_cast<ushort4*>(&lds[r][co]);
        *reinterpret_cast<ushort4*>(o + (size_t)(h0 + r) * INTER + i0 + cop) = v;
    }
}

// ---------------- 256^2 8-wave pipelined GEMM core ----------------

__device__ __forceinline__ void stage_tile(const unsigned short* Ab, const unsigned short* Bb,
                                           int ktot, int k0,
                                           unsigned short* Adst, unsigned short* Bdst,
                                           int t, int w) {
#pragma unroll
    for (int j = 0; j < 4; ++j) {
        int row = j * 64 + (t >> 3);
        int col = (t & 7) * 8;
        gload_lds16(Ab + (size_t)row * ktot + k0 + col, Adst + j * 4096 + w * 512);
        gload_lds16(Bb + (size_t)row * ktot + k0 + col, Bdst + j * 4096 + w * 512);
    }
}

#define MFMA_BF16(a, b, c) __builtin_amdgcn_mfma_f32_16x16x32_bf16(a, b, c, 0, 0, 0)
#define MEMFENCE asm volatile("" ::: "memory")

__device__ __forceinline__ void gemm_core(const unsigned short* Ab, const unsigned short* Bb,
                                          int ktot, int nkt, f32x4 (&acc)[8][4],
                                          unsigned short* lds,
                                          int t, int lane, int w, int wr, int wc) {
    unsigned short* Abuf[2] = { lds,          lds + 32768 };
    unsigned short* Bbuf[2] = { lds + 16384,  lds + 49152 };

    // prologue: K0 -> buf0, K1 -> buf1; wait K0's 8, keep K1's 8 in flight
    stage_tile(Ab, Bb, ktot, 0,  Abuf[0], Bbuf[0], t, w);
    stage_tile(Ab, Bb, ktot, 64, Abuf[1], Bbuf[1], t, w);
    asm volatile("s_waitcnt vmcnt(8)" ::: "memory");
    __builtin_amdgcn_s_barrier();
    MEMFENCE;

    const int cl  = lane & 15;
    const int kb0 = (lane >> 4) << 3;

    bf16x8 alo[4][2], ahi[4][2], blo[2][2], bhi[2][2];

    // F1 for tile 0: a-lo + b-lo
#pragma unroll
    for (int i = 0; i < 4; ++i)
#pragma unroll
        for (int k = 0; k < 2; ++k)
            alo[i][k] = ldfrag(Abuf[0], wr + i * 16 + cl, k * 32 + kb0);
#pragma unroll
    for (int j = 0; j < 2; ++j)
#pragma unroll
        for (int k = 0; k < 2; ++k)
            blo[j][k] = ldfrag(Bbuf[0], wc + j * 16 + cl, k * 32 + kb0);

    for (int kt = 0; kt < nkt; ++kt) {
        unsigned short* Ac = Abuf[kt & 1];
        unsigned short* Bc = Bbuf[kt & 1];

        // F2: a-hi (in flight during q00)
#pragma unroll
        for (int i = 0; i < 4; ++i)
#pragma unroll
            for (int k = 0; k < 2; ++k)
                ahi[i][k] = ldfrag(Ac, wr + 64 + i * 16 + cl, k * 32 + kb0);

        __builtin_amdgcn_s_barrier();
        __builtin_amdgcn_s_setprio(1);
#pragma unroll
        for (int i = 0; i < 4; ++i)          // q00: a-lo x b-lo
#pragma unroll
            for (int j = 0; j < 2; ++j)
#pragma unroll
                for (int k = 0; k < 2; ++k)
                    acc[i][j] = MFMA_BF16(alo[i][k], blo[j][k], acc[i][j]);
        __builtin_amdgcn_s_setprio(0);

        // F3: b-hi (in flight during q10)
#pragma unroll
        for (int j = 0; j < 2; ++j)
#pragma unroll
            for (int k = 0; k < 2; ++k)
                bhi[j][k] = ldfrag(Bc, wc + 32 + j * 16 + cl, k * 32 + kb0);

        __builtin_amdgcn_s_barrier();
        __builtin_amdgcn_s_setprio(1);
#pragma unroll
        for (int i = 0; i < 4; ++i)          // q10: a-hi x b-lo
#pragma unroll
            for (int j = 0; j < 2; ++j)
#pragma unroll
                for (int k = 0; k < 2; ++k)
                    acc[4 + i][j] = MFMA_BF16(ahi[i][k], blo[j][k], acc[4 + i][j]);
        __builtin_amdgcn_s_setprio(0);

        __builtin_amdgcn_s_barrier();
        __builtin_amdgcn_s_setprio(1);
#pragma unroll
        for (int i = 0; i < 4; ++i)          // q11: a-hi x b-hi
#pragma unroll
            for (int j = 0; j < 2; ++j)
#pragma unroll
                for (int k = 0; k < 2; ++k)
                    acc[4 + i][2 + j] = MFMA_BF16(ahi[i][k], bhi[j][k], acc[4 + i][2 + j]);
        __builtin_amdgcn_s_setprio(0);

        __builtin_amdgcn_s_barrier();        // all waves done reading buf kt&1
        MEMFENCE;

        // stage K(t+2) into the freed buffer; its issue overlaps q01's MFMAs
        if (kt + 2 < nkt)
            stage_tile(Ab, Bb, ktot, (kt + 2) * 64, Abuf[kt & 1], Bbuf[kt & 1], t, w);

        __builtin_amdgcn_s_setprio(1);
#pragma unroll
        for (int i = 0; i < 4; ++i)          // q01: a-lo x b-hi
#pragma unroll
            for (int j = 0; j < 2; ++j)
#pragma unroll
                for (int k = 0; k < 2; ++k)
                    acc[i][2 + j] = MFMA_BF16(alo[i][k], bhi[j][k], acc[i][2 + j]);
        __builtin_amdgcn_s_setprio(0);

        if (kt + 2 < nkt) {
            asm volatile("s_waitcnt vmcnt(8)" ::: "memory");   // K(t+1) landed
        } else if (kt + 1 < nkt) {
            asm volatile("s_waitcnt vmcnt(0)" ::: "memory");   // last staged tile
        }
        __builtin_amdgcn_s_barrier();
        MEMFENCE;

        // tail: F1 for tile kt+1 (a-lo + b-lo) — overlaps next tile's F2/q00
        if (kt + 1 < nkt) {
            unsigned short* An = Abuf[(kt + 1) & 1];
            unsigned short* Bn = Bbuf[(kt + 1) & 1];
#pragma unroll
            for (int i = 0; i < 4; ++i)
#pragma unroll
                for (int k = 0; k < 2; ++k)
                    alo[i][k] = ldfrag(An, wr + i * 16 + cl, k * 32 + kb0);
#pragma unroll
            for (int j = 0; j < 2; ++j)
#pragma unroll
                for (int k = 0; k < 2; ++k)
                    blo[j][k] = ldfrag(Bn, wc + j * 16 + cl, k * 32 + kb0);
        }
    }
}

// fc1: Xb @ w1t^T -> inter bf16 (GLU fused, swizzled store)
__global__ __launch_bounds__(512, 2) void k_fc1_8p(const unsigned short* __restrict__ Xb,
                                                   const unsigned short* __restrict__ W1T,
                                                   unsigned short* __restrict__ inter) {
    extern __shared__ unsigned short lds[];
    const int hw  = blockIdx.x;                // 1408 blocks = 8 XCDs * 176
    const int e   = hw & 7;                    // expert pinned to XCD
    const int idx = hw >> 3;
    const int mt  = idx & 3;                   // mt innermost: B-panel shared
    const int nt  = idx >> 2;
    const int t = threadIdx.x, lane = t & 63, w = t >> 6;
    const int wr = (w >> 2) * 128, wc = (w & 3) * 64;
    const int m0 = e * TOK + mt * 256;
    const int n0 = nt * 256;
    const unsigned short* Ab = Xb  + (size_t)m0 * HID;
    const unsigned short* Bb = W1T + (size_t)e * I2 * HID + (size_t)n0 * HID;

    f32x4 acc[8][4];
#pragma unroll
    for (int i = 0; i < 8; ++i)
#pragma unroll
        for (int j = 0; j < 4; ++j) acc[i][j] = f32x4{0.f, 0.f, 0.f, 0.f};

    gemm_core(Ab, Bb, HID, HID / 64, acc, lds, t, lane, w, wr, wc);

    const int cl = lane & 15;
    const int r0 = (lane >> 4) << 2;
#pragma unroll
    for (int mf = 0; mf < 8; ++mf)
#pragma unroll
        for (int nf = 0; nf < 4; ++nf)
#pragma unroll
            for (int r = 0; r < 4; ++r) {
                float v  = acc[mf][nf][r];
                float pv = __shfl_xor(v, 1);
                if ((lane & 1) == 0) {
                    float s = v / (1.f + __expf(-v)) * pv;
                    int row = m0 + wr + mf * 16 + r0 + r;
                    int pc  = n0 + wc + nf * 16 + cl;
                    int c   = pc >> 1;
                    int c2  = (c & ~63) | ((c & 63) ^ ((row & 7) << 3));
                    inter[(size_t)row * INTER + c2] = f2bf(s);
                }
            }
}

// fc2: inter @ w2t^T -> out fp32
__global__ __launch_bounds__(512, 2) void k_fc2_8p(const unsigned short* __restrict__ A,
                                                   const unsigned short* __restrict__ W2T,
                                                   float* __restrict__ out) {
    extern __shared__ unsigned short lds[];
    const int hw  = blockIdx.x;                // 256 blocks = 8 XCDs * 32
    const int e   = hw & 7;
    const int idx = hw >> 3;
    const int mt  = idx & 3;
    const int nt  = idx >> 2;
    const int t = threadIdx.x, lane = t & 63, w = t >> 6;
    const int wr = (w >> 2) * 128, wc = (w & 3) * 64;
    const int m0 = e * TOK + mt * 256;
    const int n0 = nt * 256;
    const unsigned short* Ab = A   + (size_t)m0 * INTER;
    const unsigned short* Bb = W2T + (size_t)e * HID * INTER + (size_t)n0 * INTER;

    f32x4 acc[8][4];
#pragma unroll
    for (int i = 0; i < 8; ++i)
#pragma unroll
        for (int j = 0; j < 4; ++j) acc[i][j] = f32x4{0.f, 0.f, 0.f, 0.f};

    gemm_core(Ab, Bb, INTER, INTER / 64, acc, lds, t, lane, w, wr, wc);

    const int cl = lane & 15;
    const int r0 = (lane >> 4) << 2;
#pragma unroll
    for (int mf = 0; mf < 8; ++mf)
#pragma unroll
        for (int nf = 0; nf < 4; ++nf)
#pragma unroll
            for (int r = 0; r < 4; ++r) {
                int row = m0 + wr + mf * 16 + r0 + r;
                int col = n0 + wc + nf * 16 + cl;
                out[(size_t)row * HID + col] = acc[mf][nf][r];
            }
}

// ---------------- fallback (round-1 kernels, need only 92 MB ws) ----------------

#define BM  128
#define BK  64
#define LDK 72

__global__ __launch_bounds__(256) void k_fc1_glu_fb(
    const float* __restrict__ X, const float* __restrict__ W1,
    unsigned short* __restrict__ inter)
{
    __shared__ unsigned short As[BM][LDK];
    __shared__ unsigned short Bs[128][LDK];
    const int bid = blockIdx.x;
    const int nt  = bid % (INTER / 64);
    const int mt  = (bid / (INTER / 64)) % (TOK / BM);
    const int e   = bid / ((INTER / 64) * (TOK / BM));
    const int t = threadIdx.x, lane = t & 63, w = t >> 6;
    const int m0 = mt * BM;
    const int rowbase = e * TOK + m0;
    f32x4 acc[2][8];
#pragma unroll
    for (int i = 0; i < 2; ++i)
#pragma unroll
        for (int jj = 0; jj < 8; ++jj) acc[i][jj] = f32x4{0.f, 0.f, 0.f, 0.f};
    const int jcol = t & 127;
    const int hf   = t >> 7;
    const int gcol = (jcol < 64) ? (nt * 64 + jcol) : (INTER + nt * 64 + (jcol - 64));
    const float* w1e = W1 + (size_t)e * HID * I2;
    for (int k0 = 0; k0 < HID; k0 += BK) {
#pragma unroll
        for (int it = 0; it < 8; ++it) {
            int lin = it * 256 + t;
            int r   = lin >> 4;
            int kq  = (lin & 15) << 2;
            const float4 v = *reinterpret_cast<const float4*>(
                X + (size_t)(rowbase + r) * HID + k0 + kq);
            ushort4 o;
            o.x = f2bf(v.x); o.y = f2bf(v.y); o.z = f2bf(v.z); o.w = f2bf(v.w);
            *reinterpret_cast<ushort4*>(&As[r][kq]) = o;
        }
#pragma unroll
        for (int it = 0; it < 8; ++it) {
            int kq = hf * 4 + it * 8;
            const float* p = w1e + (size_t)(k0 + kq) * I2 + gcol;
            float v0 = p[0], v1 = p[I2], v2 = p[2 * I2], v3 = p[3 * I2];
            ushort4 o;
            o.x = f2bf(v0); o.y = f2bf(v1); o.z = f2bf(v2); o.w = f2bf(v3);
            *reinterpret_cast<ushort4*>(&Bs[jcol][kq]) = o;
        }
        __syncthreads();
#pragma unroll
        for (int kk = 0; kk < 2; ++kk) {
            const int kb = kk * 32 + ((lane >> 4) << 3);
            bf16x8 a0 = *reinterpret_cast<const bf16x8*>(&As[w * 32 + (lane & 15)][kb]);
            bf16x8 a1 = *reinterpret_cast<const bf16x8*>(&As[w * 32 + 16 + (lane & 15)][kb]);
#pragma unroll
            for (int nf = 0; nf < 8; ++nf) {
                bf16x8 b = *reinterpret_cast<const bf16x8*>(&Bs[nf * 16 + (lane & 15)][kb]);
                acc[0][nf] = MFMA_BF16(a0, b, acc[0][nf]);
                acc[1][nf] = MFMA_BF16(a1, b, acc[1][nf]);
            }
        }
        __syncthreads();
    }
    const int rl0 = w * 32 + ((lane >> 4) << 2);
    const int cl  = lane & 15;
#pragma unroll
    for (int mf = 0; mf < 2; ++mf)
#pragma unroll
        for (int nfa = 0; nfa < 4; ++nfa) {
            f32x4 va = acc[mf][nfa];
            f32x4 vb = acc[mf][nfa + 4];
#pragma unroll
            for (int r = 0; r < 4; ++r) {
                float a = va[r], b = vb[r];
                float s = a / (1.f + __expf(-a)) * b;
                int row = rowbase + rl0 + mf * 16 + r;
                int col = nt * 64 + nfa * 16 + cl;
                inter[(size_t)row * INTER + col] = f2bf(s);
            }
        }
}

__global__ __launch_bounds__(256) void k_fc2_fb(
    const unsigned short* __restrict__ inter, const float* __restrict__ W2,
    float* __restrict__ out)
{
    __shared__ unsigned short As[BM][LDK];
    __shared__ unsigned short Bs[128][LDK];
    const int bid = blockIdx.x;
    const int nt  = bid % (HID / 128);
    const int mt  = (bid / (HID / 128)) % (TOK / BM);
    const int e   = bid / ((HID / 128) * (TOK / BM));
    const int t = threadIdx.x, lane = t & 63, w = t >> 6;
    const int m0 = mt * BM;
    const int rowbase = e * TOK + m0;
    f32x4 acc[2][8];
#pragma unroll
    for (int i = 0; i < 2; ++i)
#pragma unroll
        for (int jj = 0; jj < 8; ++jj) acc[i][jj] = f32x4{0.f, 0.f, 0.f, 0.f};
    const int jcol = t & 127;
    const int hf   = t >> 7;
    const int gcol = nt * 128 + jcol;
    const float* w2e = W2 + (size_t)e * INTER * HID;
    for (int k0 = 0; k0 < INTER; k0 += BK) {
#pragma unroll
        for (int it = 0; it < 4; ++it) {
            int lin = it * 256 + t;
            int r   = lin >> 3;
            int kq  = (lin & 7) << 3;
            uint4 v = *reinterpret_cast<const uint4*>(
                inter + (size_t)(rowbase + r) * INTER + k0 + kq);
            *reinterpret_cast<uint4*>(&As[r][kq]) = v;
        }
#pragma unroll
        for (int it = 0; it < 8; ++it) {
            int kq = hf * 4 + it * 8;
            const float* p = w2e + (size_t)(k0 + kq) * HID + gcol;
            float v0 = p[0], v1 = p[HID], v2 = p[2 * HID], v3 = p[3 * HID];
            ushort4 o;
            o.x = f2bf(v0); o.y = f2bf(v1); o.z = f2bf(v2); o.w = f2bf(v3);
            *reinterpret_cast<ushort4*>(&Bs[jcol][kq]) = o;
        }
        __syncthreads();
#pragma unroll
        for (int kk = 0; kk < 2; ++kk) {
            const int kb = kk * 32 + ((lane >> 4) << 3);
            bf16x8 a0 = *reinterpret_cast<const bf16x8*>(&As[w * 32 + (lane & 15)][kb]);
            bf16x8 a1 = *reinterpret_cast<const bf16x8*>(&As[w * 32 + 16 + (lane & 15)][kb]);
#pragma unroll
            for (int nf = 0; nf < 8; ++nf) {
                bf16x8 b = *reinterpret_cast<const bf16x8*>(&Bs[nf * 16 + (lane & 15)][kb]);
                acc[0][nf] = MFMA_BF16(a0, b, acc[0][nf]);
                acc[1][nf] = MFMA_BF16(a1, b, acc[1][nf]);
            }
        }
        __syncthreads();
    }
    const int rl0 = w * 32 + ((lane >> 4) << 2);
    const int cl  = lane & 15;
#pragma unroll
    for (int mf = 0; mf < 2; ++mf)
#pragma unroll
        for (int nf = 0; nf < 8; ++nf) {
            f32x4 v = acc[mf][nf];
#pragma unroll
            for (int r = 0; r < 4; ++r) {
                int row = rowbase + rl0 + mf * 16 + r;
                int col = nt * 128 + nf * 16 + cl;
                out[(size_t)row * HID + col] = v[r];
            }
        }
}

// ---------------- launch ----------------

extern "C" void kernel_launch(void* const* d_in, const int* in_sizes, int n_in,
                              void* d_out, int out_size, void* d_ws, size_t ws_size,
                              hipStream_t stream) {
    const float* X  = (const float*)d_in[0];
    const float* W1 = (const float*)d_in[1];
    const float* W2 = (const float*)d_in[2];
    float* out = (float*)d_out;

    const size_t XB_B  = (size_t)EXPERTS * TOK * HID * 2;
    const size_t W1T_B = (size_t)EXPERTS * I2 * HID * 2;
    const size_t W2T_B = (size_t)EXPERTS * HID * INTER * 2;
    const size_t INT_B = (size_t)EXPERTS * TOK * INTER * 2;
    const size_t need  = XB_B + W1T_B + W2T_B + INT_B;

    if (ws_size >= need) {
        unsigned short* Xb    = (unsigned short*)d_ws;
        unsigned short* w1t   = (unsigned short*)((char*)d_ws + XB_B);
        unsigned short* w2t   = (unsigned short*)((char*)d_ws + XB_B + W1T_B);
        unsigned short* inter = (unsigned short*)((char*)d_ws + XB_B + W1T_B + W2T_B);

        hipFuncSetAttribute((const void*)k_fc1_8p,
            hipFuncAttributeMaxDynamicSharedMemorySize, 131072);
        hipFuncSetAttribute((const void*)k_fc2_8p,
            hipFuncAttributeMaxDynamicSharedMemorySize, 131072);

        dim3 b256(256), b512(512);
        k_cvt_x <<<(EXPERTS * TOK * HID) / (256 * 8), b256, 0, stream>>>(X, Xb);
        k_cvt_w1<<<EXPERTS * (I2 / 64) * (HID / 64),   b256, 0, stream>>>(W1, w1t);
        k_cvt_w2<<<EXPERTS * (HID / 64) * (INTER / 64), b256, 0, stream>>>(W2, w2t);
        k_fc1_8p<<<EXPERTS * 4 * (I2 / 256),  b512, 131072, stream>>>(Xb, w1t, inter);
        k_fc2_8p<<<EXPERTS * 4 * (HID / 256), b512, 131072, stream>>>(inter, w2t, out);
    } else {
        unsigned short* inter = (unsigned short*)d_ws;
        dim3 b256(256);
        k_fc1_glu_fb<<<EXPERTS * (TOK / BM) * (INTER / 64), b256, 0, stream>>>(X, W1, inter);
        k_fc2_fb    <<<EXPERTS * (TOK / BM) * (HID / 128),  b256, 0, stream>>>(inter, W2, out);
    }
}

// Round 6
// 1200.654 us; speedup vs baseline: 2.4820x; 2.4820x over previous
//
#include <hip/hip_runtime.h>
#include <hip/hip_bf16.h>

// GroupedMLP: E=8, T=1024, H=2048, I=5632
// Round 6: 256x256x64 8-wave dbuf GEMM, counted vmcnt(8), T2 swizzle via ws
// layouts, mt-innermost XCD ordering. Inner schedule rebuilt after round-5
// spill (WRITE_SIZE 2GB): hold B-frags (32 VGPR) per K-tile, stream A-frags
// one m-frag ahead (16 VGPR ping-pong), 8 micro-clusters of {2 ds_read -> 8
// MFMA}, NO intra-tile barriers (compiler emits counted lgkmcnt). 2 barriers
// per K-tile total (around stage). Peak live ~200 VGPR -> no spill.

#define EXPERTS 8
#define TOK     1024
#define HID     2048
#define INTER   5632
#define I2      (2 * INTER)

typedef __bf16 bf16x8 __attribute__((ext_vector_type(8)));
typedef float  f32x4  __attribute__((ext_vector_type(4)));

__device__ __forceinline__ unsigned short f2bf(float f) {
    union { float f; unsigned u; } v; v.f = f;
    unsigned r = v.u + 0x7FFFu + ((v.u >> 16) & 1u);   // RNE
    return (unsigned short)(r >> 16);
}

__device__ __forceinline__ void gload_lds16(const void* g, void* l) {
    __builtin_amdgcn_global_load_lds(
        (const __attribute__((address_space(1))) void*)g,
        (__attribute__((address_space(3))) void*)l, 16, 0, 0);
}

// swizzled fragment read: tile is [256][64] bf16, element k-slot XORed by row&7
__device__ __forceinline__ bf16x8 ldfrag(const unsigned short* S, int R, int kb) {
    int off = R * 64 + (kb ^ ((R & 7) << 3));
    return *reinterpret_cast<const bf16x8*>(S + off);
}

// ---------------- converts (write swizzled ws layouts) ----------------

__global__ __launch_bounds__(256) void k_cvt_x(const float* __restrict__ X,
                                               unsigned short* __restrict__ Xb) {
    size_t base = ((size_t)blockIdx.x * 256 + threadIdx.x) * 8;
    int row = (int)(base >> 11);
    int k   = (int)(base & (HID - 1));
    int kp  = k ^ ((row & 7) << 3);
    float4 v0 = *reinterpret_cast<const float4*>(X + base);
    float4 v1 = *reinterpret_cast<const float4*>(X + base + 4);
    uint4 o;
    o.x = (unsigned)f2bf(v0.x) | ((unsigned)f2bf(v0.y) << 16);
    o.y = (unsigned)f2bf(v0.z) | ((unsigned)f2bf(v0.w) << 16);
    o.z = (unsigned)f2bf(v1.x) | ((unsigned)f2bf(v1.y) << 16);
    o.w = (unsigned)f2bf(v1.z) | ((unsigned)f2bf(v1.w) << 16);
    *reinterpret_cast<uint4*>(Xb + (size_t)row * HID + kp) = o;
}

__global__ __launch_bounds__(256) void k_cvt_w1(const float* __restrict__ W1,
                                                unsigned short* __restrict__ W1T) {
    __shared__ unsigned short lds[64][72];
    const int bid = blockIdx.x;
    const int hb = bid % (HID / 64);
    const int pb = (bid / (HID / 64)) % (I2 / 64);
    const int e  = bid / ((HID / 64) * (I2 / 64));
    const int h0 = hb * 64, p0 = pb * 64, n0 = p0 >> 1;
    const float* w1e = W1 + (size_t)e * HID * I2;
    const int t = threadIdx.x;
#pragma unroll
    for (int it = 0; it < 16; ++it) {
        int lin   = it * 256 + t;
        int n_off = lin & 31;
        int c     = (lin >> 5) & 1;
        int h_off = lin >> 6;
        float v = w1e[(size_t)(h0 + h_off) * I2 + c * INTER + n0 + n_off];
        lds[2 * n_off + c][h_off] = f2bf(v);
    }
    __syncthreads();
    unsigned short* o = W1T + (size_t)e * I2 * HID;
#pragma unroll
    for (int it = 0; it < 4; ++it) {
        int lin = it * 256 + t;
        int r   = lin >> 4;
        int co  = (lin & 15) * 4;
        int cop = co ^ ((r & 7) << 3);
        ushort4 v = *reinterpret_cast<ushort4*>(&lds[r][co]);
        *reinterpret_cast<ushort4*>(o + (size_t)(p0 + r) * HID + h0 + cop) = v;
    }
}

__global__ __launch_bounds__(256) void k_cvt_w2(const float* __restrict__ W2,
                                                unsigned short* __restrict__ W2T) {
    __shared__ unsigned short lds[64][72];
    const int bid = blockIdx.x;
    const int ib = bid % (INTER / 64);
    const int hb = (bid / (INTER / 64)) % (HID / 64);
    const int e  = bid / ((INTER / 64) * (HID / 64));
    const int i0 = ib * 64, h0 = hb * 64;
    const float* w2e = W2 + (size_t)e * INTER * HID;
    const int t = threadIdx.x;
#pragma unroll
    for (int it = 0; it < 16; ++it) {
        int lin   = it * 256 + t;
        int h_off = lin & 63;
        int i_off = lin >> 6;
        float v = w2e[(size_t)(i0 + i_off) * HID + h0 + h_off];
        lds[h_off][i_off] = f2bf(v);
    }
    __syncthreads();
    unsigned short* o = W2T + (size_t)e * HID * INTER;
#pragma unroll
    for (int it = 0; it < 4; ++it) {
        int lin = it * 256 + t;
        int r   = lin >> 4;
        int co  = (lin & 15) * 4;
        int cop = co ^ ((r & 7) << 3);
        ushort4 v = *reinterpret_cast<ushort4*>(&lds[r][co]);
        *reinterpret_cast<ushort4*>(o + (size_t)(h0 + r) * INTER + i0 + cop) = v;
    }
}

// ---------------- 256^2 8-wave GEMM core, streamed-A schedule ----------------

__device__ __forceinline__ void stage_tile(const unsigned short* Ab, const unsigned short* Bb,
                                           int ktot, int k0,
                                           unsigned short* Adst, unsigned short* Bdst,
                                           int t, int w) {
#pragma unroll
    for (int j = 0; j < 4; ++j) {
        int row = j * 64 + (t >> 3);
        int col = (t & 7) * 8;
        gload_lds16(Ab + (size_t)row * ktot + k0 + col, Adst + j * 4096 + w * 512);
        gload_lds16(Bb + (size_t)row * ktot + k0 + col, Bdst + j * 4096 + w * 512);
    }
}

#define MFMA_BF16(a, b, c) __builtin_amdgcn_mfma_f32_16x16x32_bf16(a, b, c, 0, 0, 0)
#define MEMFENCE asm volatile("" ::: "memory")

__device__ __forceinline__ void gemm_core(const unsigned short* Ab, const unsigned short* Bb,
                                          int ktot, int nkt, f32x4 (&acc)[8][4],
                                          unsigned short* lds,
                                          int t, int lane, int w, int wr, int wc) {
    unsigned short* Abuf[2] = { lds,          lds + 32768 };
    unsigned short* Bbuf[2] = { lds + 16384,  lds + 49152 };

    // prologue: K0 -> buf0, K1 -> buf1; wait K0's 8, keep K1's 8 in flight
    stage_tile(Ab, Bb, ktot, 0,  Abuf[0], Bbuf[0], t, w);
    stage_tile(Ab, Bb, ktot, 64, Abuf[1], Bbuf[1], t, w);
    asm volatile("s_waitcnt vmcnt(8)" ::: "memory");
    __builtin_amdgcn_s_barrier();
    MEMFENCE;

    const int cl  = lane & 15;
    const int kb0 = (lane >> 4) << 3;

    bf16x8 b[4][2];       // all B-frags for current tile (held whole tile)
    bf16x8 areg[2][2];    // A-frag ping-pong (current / next m-frag)

    // tile-0 operands: all B + A-frag 0
#pragma unroll
    for (int j = 0; j < 4; ++j)
#pragma unroll
        for (int k = 0; k < 2; ++k)
            b[j][k] = ldfrag(Bbuf[0], wc + j * 16 + cl, k * 32 + kb0);
#pragma unroll
    for (int k = 0; k < 2; ++k)
        areg[0][k] = ldfrag(Abuf[0], wr + cl, k * 32 + kb0);

    for (int kt = 0; kt < nkt; ++kt) {
        unsigned short* Ac = Abuf[kt & 1];

        // 8 micro-clusters: issue next A-frag reads, then 8 MFMA on current.
        // No barriers here — compiler inserts counted lgkmcnt per dataflow;
        // waves drift so LDS reads overlap other waves' MFMAs.
#pragma unroll
        for (int mf = 0; mf < 8; ++mf) {
            if (mf < 7) {
#pragma unroll
                for (int k = 0; k < 2; ++k)
                    areg[(mf + 1) & 1][k] =
                        ldfrag(Ac, wr + (mf + 1) * 16 + cl, k * 32 + kb0);
            }
            __builtin_amdgcn_s_setprio(1);
#pragma unroll
            for (int j = 0; j < 4; ++j)
#pragma unroll
                for (int k = 0; k < 2; ++k)
                    acc[mf][j] = MFMA_BF16(areg[mf & 1][k], b[j][k], acc[mf][j]);
            __builtin_amdgcn_s_setprio(0);
        }

        __builtin_amdgcn_s_barrier();      // all waves done reading buf kt&1
        MEMFENCE;

        // stage K(t+2) into the freed buffer; counted wait for K(t+1)
        if (kt + 2 < nkt) {
            stage_tile(Ab, Bb, ktot, (kt + 2) * 64, Abuf[kt & 1], Bbuf[kt & 1], t, w);
            asm volatile("s_waitcnt vmcnt(8)" ::: "memory");
        } else if (kt + 1 < nkt) {
            asm volatile("s_waitcnt vmcnt(0)" ::: "memory");
        }
        __builtin_amdgcn_s_barrier();
        MEMFENCE;

        // operands for tile kt+1: all B + A-frag 0
        if (kt + 1 < nkt) {
            unsigned short* An = Abuf[(kt + 1) & 1];
            unsigned short* Bn = Bbuf[(kt + 1) & 1];
#pragma unroll
            for (int j = 0; j < 4; ++j)
#pragma unroll
                for (int k = 0; k < 2; ++k)
                    b[j][k] = ldfrag(Bn, wc + j * 16 + cl, k * 32 + kb0);
#pragma unroll
            for (int k = 0; k < 2; ++k)
                areg[0][k] = ldfrag(An, wr + cl, k * 32 + kb0);
        }
    }
}

// fc1: Xb @ w1t^T -> inter bf16 (GLU fused, swizzled store)
__global__ __launch_bounds__(512, 2) void k_fc1_8p(const unsigned short* __restrict__ Xb,
                                                   const unsigned short* __restrict__ W1T,
                                                   unsigned short* __restrict__ inter) {
    extern __shared__ unsigned short lds[];
    const int hw  = blockIdx.x;                // 1408 blocks = 8 XCDs * 176
    const int e   = hw & 7;                    // expert pinned to XCD
    const int idx = hw >> 3;
    const int mt  = idx & 3;                   // mt innermost: B-panel shared
    const int nt  = idx >> 2;
    const int t = threadIdx.x, lane = t & 63, w = t >> 6;
    const int wr = (w >> 2) * 128, wc = (w & 3) * 64;
    const int m0 = e * TOK + mt * 256;
    const int n0 = nt * 256;
    const unsigned short* Ab = Xb  + (size_t)m0 * HID;
    const unsigned short* Bb = W1T + (size_t)e * I2 * HID + (size_t)n0 * HID;

    f32x4 acc[8][4];
#pragma unroll
    for (int i = 0; i < 8; ++i)
#pragma unroll
        for (int j = 0; j < 4; ++j) acc[i][j] = f32x4{0.f, 0.f, 0.f, 0.f};

    gemm_core(Ab, Bb, HID, HID / 64, acc, lds, t, lane, w, wr, wc);

    const int cl = lane & 15;
    const int r0 = (lane >> 4) << 2;
#pragma unroll
    for (int mf = 0; mf < 8; ++mf)
#pragma unroll
        for (int nf = 0; nf < 4; ++nf)
#pragma unroll
            for (int r = 0; r < 4; ++r) {
                float v  = acc[mf][nf][r];
                float pv = __shfl_xor(v, 1);
                if ((lane & 1) == 0) {
                    float s = v / (1.f + __expf(-v)) * pv;
                    int row = m0 + wr + mf * 16 + r0 + r;
                    int pc  = n0 + wc + nf * 16 + cl;
                    int c   = pc >> 1;
                    int c2  = (c & ~63) | ((c & 63) ^ ((row & 7) << 3));
                    inter[(size_t)row * INTER + c2] = f2bf(s);
                }
            }
}

// fc2: inter @ w2t^T -> out fp32
__global__ __launch_bounds__(512, 2) void k_fc2_8p(const unsigned short* __restrict__ A,
                                                   const unsigned short* __restrict__ W2T,
                                                   float* __restrict__ out) {
    extern __shared__ unsigned short lds[];
    const int hw  = blockIdx.x;                // 256 blocks = 8 XCDs * 32
    const int e   = hw & 7;
    const int idx = hw >> 3;
    const int mt  = idx & 3;
    const int nt  = idx >> 2;
    const int t = threadIdx.x, lane = t & 63, w = t >> 6;
    const int wr = (w >> 2) * 128, wc = (w & 3) * 64;
    const int m0 = e * TOK + mt * 256;
    const int n0 = nt * 256;
    const unsigned short* Ab = A   + (size_t)m0 * INTER;
    const unsigned short* Bb = W2T + (size_t)e * HID * INTER + (size_t)n0 * INTER;

    f32x4 acc[8][4];
#pragma unroll
    for (int i = 0; i < 8; ++i)
#pragma unroll
        for (int j = 0; j < 4; ++j) acc[i][j] = f32x4{0.f, 0.f, 0.f, 0.f};

    gemm_core(Ab, Bb, INTER, INTER / 64, acc, lds, t, lane, w, wr, wc);

    const int cl = lane & 15;
    const int r0 = (lane >> 4) << 2;
#pragma unroll
    for (int mf = 0; mf < 8; ++mf)
#pragma unroll
        for (int nf = 0; nf < 4; ++nf)
#pragma unroll
            for (int r = 0; r < 4; ++r) {
                int row = m0 + wr + mf * 16 + r0 + r;
                int col = n0 + wc + nf * 16 + cl;
                out[(size_t)row * HID + col] = acc[mf][nf][r];
            }
}

// ---------------- fallback (round-1 kernels, need only 92 MB ws) ----------------

#define BM  128
#define BK  64
#define LDK 72

__global__ __launch_bounds__(256) void k_fc1_glu_fb(
    const float* __restrict__ X, const float* __restrict__ W1,
    unsigned short* __restrict__ inter)
{
    __shared__ unsigned short As[BM][LDK];
    __shared__ unsigned short Bs[128][LDK];
    const int bid = blockIdx.x;
    const int nt  = bid % (INTER / 64);
    const int mt  = (bid / (INTER / 64)) % (TOK / BM);
    const int e   = bid / ((INTER / 64) * (TOK / BM));
    const int t = threadIdx.x, lane = t & 63, w = t >> 6;
    const int m0 = mt * BM;
    const int rowbase = e * TOK + m0;
    f32x4 acc[2][8];
#pragma unroll
    for (int i = 0; i < 2; ++i)
#pragma unroll
        for (int jj = 0; jj < 8; ++jj) acc[i][jj] = f32x4{0.f, 0.f, 0.f, 0.f};
    const int jcol = t & 127;
    const int hf   = t >> 7;
    const int gcol = (jcol < 64) ? (nt * 64 + jcol) : (INTER + nt * 64 + (jcol - 64));
    const float* w1e = W1 + (size_t)e * HID * I2;
    for (int k0 = 0; k0 < HID; k0 += BK) {
#pragma unroll
        for (int it = 0; it < 8; ++it) {
            int lin = it * 256 + t;
            int r   = lin >> 4;
            int kq  = (lin & 15) << 2;
            const float4 v = *reinterpret_cast<const float4*>(
                X + (size_t)(rowbase + r) * HID + k0 + kq);
            ushort4 o;
            o.x = f2bf(v.x); o.y = f2bf(v.y); o.z = f2bf(v.z); o.w = f2bf(v.w);
            *reinterpret_cast<ushort4*>(&As[r][kq]) = o;
        }
#pragma unroll
        for (int it = 0; it < 8; ++it) {
            int kq = hf * 4 + it * 8;
            const float* p = w1e + (size_t)(k0 + kq) * I2 + gcol;
            float v0 = p[0], v1 = p[I2], v2 = p[2 * I2], v3 = p[3 * I2];
            ushort4 o;
            o.x = f2bf(v0); o.y = f2bf(v1); o.z = f2bf(v2); o.w = f2bf(v3);
            *reinterpret_cast<ushort4*>(&Bs[jcol][kq]) = o;
        }
        __syncthreads();
#pragma unroll
        for (int kk = 0; kk < 2; ++kk) {
            const int kb = kk * 32 + ((lane >> 4) << 3);
            bf16x8 a0 = *reinterpret_cast<const bf16x8*>(&As[w * 32 + (lane & 15)][kb]);
            bf16x8 a1 = *reinterpret_cast<const bf16x8*>(&As[w * 32 + 16 + (lane & 15)][kb]);
#pragma unroll
            for (int nf = 0; nf < 8; ++nf) {
                bf16x8 b = *reinterpret_cast<const bf16x8*>(&Bs[nf * 16 + (lane & 15)][kb]);
                acc[0][nf] = MFMA_BF16(a0, b, acc[0][nf]);
                acc[1][nf] = MFMA_BF16(a1, b, acc[1][nf]);
            }
        }
        __syncthreads();
    }
    const int rl0 = w * 32 + ((lane >> 4) << 2);
    const int cl  = lane & 15;
#pragma unroll
    for (int mf = 0; mf < 2; ++mf)
#pragma unroll
        for (int nfa = 0; nfa < 4; ++nfa) {
            f32x4 va = acc[mf][nfa];
            f32x4 vb = acc[mf][nfa + 4];
#pragma unroll
            for (int r = 0; r < 4; ++r) {
                float a = va[r], b = vb[r];
                float s = a / (1.f + __expf(-a)) * b;
                int row = rowbase + rl0 + mf * 16 + r;
                int col = nt * 64 + nfa * 16 + cl;
                inter[(size_t)row * INTER + col] = f2bf(s);
            }
        }
}

__global__ __launch_bounds__(256) void k_fc2_fb(
    const unsigned short* __restrict__ inter, const float* __restrict__ W2,
    float* __restrict__ out)
{
    __shared__ unsigned short As[BM][LDK];
    __shared__ unsigned short Bs[128][LDK];
    const int bid = blockIdx.x;
    const int nt  = bid % (HID / 128);
    const int mt  = (bid / (HID / 128)) % (TOK / BM);
    const int e   = bid / ((HID / 128) * (TOK / BM));
    const int t = threadIdx.x, lane = t & 63, w = t >> 6;
    const int m0 = mt * BM;
    const int rowbase = e * TOK + m0;
    f32x4 acc[2][8];
#pragma unroll
    for (int i = 0; i < 2; ++i)
#pragma unroll
        for (int jj = 0; jj < 8; ++jj) acc[i][jj] = f32x4{0.f, 0.f, 0.f, 0.f};
    const int jcol = t & 127;
    const int hf   = t >> 7;
    const int gcol = nt * 128 + jcol;
    const float* w2e = W2 + (size_t)e * INTER * HID;
    for (int k0 = 0; k0 < INTER; k0 += BK) {
#pragma unroll
        for (int it = 0; it < 4; ++it) {
            int lin = it * 256 + t;
            int r   = lin >> 3;
            int kq  = (lin & 7) << 3;
            uint4 v = *reinterpret_cast<const uint4*>(
                inter + (size_t)(rowbase + r) * INTER + k0 + kq);
            *reinterpret_cast<uint4*>(&As[r][kq]) = v;
        }
#pragma unroll
        for (int it = 0; it < 8; ++it) {
            int kq = hf * 4 + it * 8;
            const float* p = w2e + (size_t)(k0 + kq) * HID + gcol;
            float v0 = p[0], v1 = p[HID], v2 = p[2 * HID], v3 = p[3 * HID];
            ushort4 o;
            o.x = f2bf(v0); o.y = f2bf(v1); o.z = f2bf(v2); o.w = f2bf(v3);
            *reinterpret_cast<ushort4*>(&Bs[jcol][kq]) = o;
        }
        __syncthreads();
#pragma unroll
        for (int kk = 0; kk < 2; ++kk) {
            const int kb = kk * 32 + ((lane >> 4) << 3);
            bf16x8 a0 = *reinterpret_cast<const bf16x8*>(&As[w * 32 + (lane & 15)][kb]);
            bf16x8 a1 = *reinterpret_cast<const bf16x8*>(&As[w * 32 + 16 + (lane & 15)][kb]);
#pragma unroll
            for (int nf = 0; nf < 8; ++nf) {
                bf16x8 b = *reinterpret_cast<const bf16x8*>(&Bs[nf * 16 + (lane & 15)][kb]);
                acc[0][nf] = MFMA_BF16(a0, b, acc[0][nf]);
                acc[1][nf] = MFMA_BF16(a1, b, acc[1][nf]);
            }
        }
        __syncthreads();
    }
    const int rl0 = w * 32 + ((lane >> 4) << 2);
    const int cl  = lane & 15;
#pragma unroll
    for (int mf = 0; mf < 2; ++mf)
#pragma unroll
        for (int nf = 0; nf < 8; ++nf) {
            f32x4 v = acc[mf][nf];
#pragma unroll
            for (int r = 0; r < 4; ++r) {
                int row = rowbase + rl0 + mf * 16 + r;
                int col = nt * 128 + nf * 16 + cl;
                out[(size_t)row * HID + col] = v[r];
            }
        }
}

// ---------------- launch ----------------

extern "C" void kernel_launch(void* const* d_in, const int* in_sizes, int n_in,
                              void* d_out, int out_size, void* d_ws, size_t ws_size,
                              hipStream_t stream) {
    const float* X  = (const float*)d_in[0];
    const float* W1 = (const float*)d_in[1];
    const float* W2 = (const float*)d_in[2];
    float* out = (float*)d_out;

    const size_t XB_B  = (size_t)EXPERTS * TOK * HID * 2;
    const size_t W1T_B = (size_t)EXPERTS * I2 * HID * 2;
    const size_t W2T_B = (size_t)EXPERTS * HID * INTER * 2;
    const size_t INT_B = (size_t)EXPERTS * TOK * INTER * 2;
    const size_t need  = XB_B + W1T_B + W2T_B + INT_B;

    if (ws_size >= need) {
        unsigned short* Xb    = (unsigned short*)d_ws;
        unsigned short* w1t   = (unsigned short*)((char*)d_ws + XB_B);
        unsigned short* w2t   = (unsigned short*)((char*)d_ws + XB_B + W1T_B);
        unsigned short* inter = (unsigned short*)((char*)d_ws + XB_B + W1T_B + W2T_B);

        hipFuncSetAttribute((const void*)k_fc1_8p,
            hipFuncAttributeMaxDynamicSharedMemorySize, 131072);
        hipFuncSetAttribute((const void*)k_fc2_8p,
            hipFuncAttributeMaxDynamicSharedMemorySize, 131072);

        dim3 b256(256), b512(512);
        k_cvt_x <<<(EXPERTS * TOK * HID) / (256 * 8), b256, 0, stream>>>(X, Xb);
        k_cvt_w1<<<EXPERTS * (I2 / 64) * (HID / 64),   b256, 0, stream>>>(W1, w1t);
        k_cvt_w2<<<EXPERTS * (HID / 64) * (INTER / 64), b256, 0, stream>>>(W2, w2t);
        k_fc1_8p<<<EXPERTS * 4 * (I2 / 256),  b512, 131072, stream>>>(Xb, w1t, inter);
        k_fc2_8p<<<EXPERTS * 4 * (HID / 256), b512, 131072, stream>>>(inter, w2t, out);
    } else {
        unsigned short* inter = (unsigned short*)d_ws;
        dim3 b256(256);
        k_fc1_glu_fb<<<EXPERTS * (TOK / BM) * (INTER / 64), b256, 0, stream>>>(X, W1, inter);
        k_fc2_fb    <<<EXPERTS * (TOK / BM) * (HID / 128),  b256, 0, stream>>>(inter, W2, out);
    }
}